// Round 2
// baseline (102.331 us; speedup 1.0000x reference)
//
#include <hip/hip_runtime.h>

// DepthOffset: per (b, tap j, oy, ox) argmin_k |sample(j,k) - center|.
// sample(j,k) at (oy+4(jr-1)+2(kr-1), ox+4(jc-1)+2(kc-1)); two-stage zero pad:
//  stage1: tap origin (oy+4(jr-1), ox+4(jc-1)) out of bounds -> ALL 9 samples = 0
//          -> all diffs tie at |center| -> argmin = first allowed k (constant)
//  stage2: final position out of bounds -> 0  (handled by pre-padded buffer)
// masks: taps 1,7 allow only kc==1; taps 3,5 allow only kr==1.
// out[b,j] = (k/3-1)*2 ; out[b,9+j] = (k%3-1)*2

#define BATCH 4
#define IH 480
#define IW 640
#define PPW 656  // 6 left + 640 + 10 right  (mult of 4 -> rows 16B aligned)
#define PPH 492  // 6 top + 480 + 6 bottom
#define PADBYTES ((size_t)BATCH * PPH * PPW * 4)

// ---------------- pad kernel: d (4,480,640) -> pd (4,492,656) zero-padded ---
__global__ __launch_bounds__(256) void pad_kernel(const float* __restrict__ d,
                                                  float* __restrict__ pd) {
  int idx = blockIdx.x * blockDim.x + threadIdx.x;
  const int n4 = BATCH * PPH * (PPW / 4);
  if (idx >= n4) return;
  int c4 = idx % (PPW / 4);
  int t = idx / (PPW / 4);
  int r = t % PPH;
  int b = t / PPH;
  int y = r - 6;
  float4 v = make_float4(0.f, 0.f, 0.f, 0.f);
  if ((unsigned)y < (unsigned)IH) {
    const float* src = d + ((size_t)b * IH + y) * IW;
    int xb = c4 * 4 - 6;
    float* vp = (float*)&v;
#pragma unroll
    for (int q = 0; q < 4; ++q) {
      int x = xb + q;
      if ((unsigned)x < (unsigned)IW) vp[q] = src[x];
    }
  }
  ((float4*)pd)[idx] = v;
}

// ---------------- main kernel: 4 pixels/thread, padded input, no bounds ------
// Window for pixel group x0..x0+3 at row oy: padded rows oy+2i (i=0..6),
// padded cols x0..x0+15.  window[i][c] <-> image (oy+2i-6, x0+c-6).
// Tap (jr,jc) shift (kr,kc) for pixel p: window[2jr+kr][p + 4jc + 2kc].
__global__ __launch_bounds__(256) void depth_offset_main(
    const float* __restrict__ pd, int* __restrict__ out) {
  const int NG = IW / 4;  // 160 groups per row
  int g = blockIdx.x * blockDim.x + threadIdx.x;
  if (g >= BATCH * IH * NG) return;
  int gx = g % NG;
  int t = g / NG;
  int oy = t % IH;
  int b = t / IH;
  int x0 = gx * 4;

  const float* base = pd + ((size_t)b * PPH + oy) * PPW + x0;

  float r0[16], r1[16], r2[16], r3[16], r4[16], r5[16], r6[16];
#define LDROW(arr, i)                                              \
  {                                                                \
    const float4* rp = (const float4*)(base + (size_t)(2 * (i)) * PPW); \
    *(float4*)&arr[0] = rp[0];                                     \
    *(float4*)&arr[4] = rp[1];                                     \
    *(float4*)&arr[8] = rp[2];                                     \
    *(float4*)&arr[12] = rp[3];                                    \
  }

  const size_t plane = (size_t)IH * IW;
  int* obase = out + (size_t)b * 18 * plane + (size_t)oy * IW + x0;
#define STORE2(J, oh, ow)                                          \
  {                                                                \
    *(int4*)(obase + (size_t)(J)*plane) =                          \
        make_int4(oh[0], oh[1], oh[2], oh[3]);                     \
    *(int4*)(obase + (size_t)(9 + (J)) * plane) =                  \
        make_int4(ow[0], ow[1], ow[2], ow[3]);                     \
  }

  bool yok0 = (oy >= 4), yok2 = (oy <= IH - 5);
  bool xokL[4], xokR[4];
#pragma unroll
  for (int p = 0; p < 4; ++p) {
    xokL[p] = (x0 + p >= 4);
    xokR[p] = (x0 + p <= IW - 5);
  }

#define CAND(val, H, W)                  \
  {                                      \
    float df = fabsf((val)-cc);          \
    if (df < best) {                     \
      best = df;                         \
      bh = (H);                          \
      bw = (W);                          \
    }                                    \
  }

  // 9-candidate tap (corners + center): rows RA,RB,RC (kr=0,1,2), cols cb+2*kc
#define DO_TAP9(J, RA, RB, RC, JC4, OKEXPR, FH, FW)                 \
  {                                                                 \
    int oh[4], ow[4];                                               \
    _Pragma("unroll") for (int p = 0; p < 4; ++p) {                 \
      float cc = cen[p];                                            \
      int cb = p + (JC4);                                           \
      float best = fabsf(RA[cb] - cc);                              \
      int bh = -2, bw = -2;                                         \
      CAND(RA[cb + 2], -2, 0)                                       \
      CAND(RA[cb + 4], -2, 2)                                       \
      CAND(RB[cb], 0, -2)                                           \
      CAND(RB[cb + 2], 0, 0)                                        \
      CAND(RB[cb + 4], 0, 2)                                        \
      CAND(RC[cb], 2, -2)                                           \
      CAND(RC[cb + 2], 2, 0)                                        \
      CAND(RC[cb + 4], 2, 2)                                        \
      bool ok = (OKEXPR);                                           \
      oh[p] = ok ? bh : (FH);                                       \
      ow[p] = ok ? bw : (FW);                                       \
    }                                                               \
    STORE2(J, oh, ow)                                               \
  }

  // vertical edge tap (j=1,7): col p+6, rows RA,RB,RC; ow always 0; fb oh=-2
#define DO_TAPV(J, RA, RB, RC, OKEXPR)                              \
  {                                                                 \
    int oh[4], ow[4];                                               \
    _Pragma("unroll") for (int p = 0; p < 4; ++p) {                 \
      float cc = cen[p];                                            \
      int cb = p + 6;                                               \
      float best = fabsf(RA[cb] - cc);                              \
      int bh = -2;                                                  \
      {                                                             \
        float df = fabsf(RB[cb] - cc);                              \
        if (df < best) { best = df; bh = 0; }                       \
      }                                                             \
      {                                                             \
        float df = fabsf(RC[cb] - cc);                              \
        if (df < best) { best = df; bh = 2; }                       \
      }                                                             \
      bool ok = (OKEXPR);                                           \
      oh[p] = ok ? bh : -2;                                         \
      ow[p] = 0;                                                    \
    }                                                               \
    STORE2(J, oh, ow)                                               \
  }

  // horizontal edge tap (j=3,5): row R, cols cb,cb+2,cb+4; oh always 0; fb ow=-2
#define DO_TAPH(J, R, JC4, OKEXPR)                                  \
  {                                                                 \
    int oh[4], ow[4];                                               \
    _Pragma("unroll") for (int p = 0; p < 4; ++p) {                 \
      float cc = cen[p];                                            \
      int cb = p + (JC4);                                           \
      float best = fabsf(R[cb] - cc);                               \
      int bw = -2;                                                  \
      {                                                             \
        float df = fabsf(R[cb + 2] - cc);                           \
        if (df < best) { best = df; bw = 0; }                       \
      }                                                             \
      {                                                             \
        float df = fabsf(R[cb + 4] - cc);                           \
        if (df < best) { best = df; bw = 2; }                       \
      }                                                             \
      bool ok = (OKEXPR);                                           \
      oh[p] = 0;                                                    \
      ow[p] = ok ? bw : -2;                                         \
    }                                                               \
    STORE2(J, oh, ow)                                               \
  }

  // Phase A: taps jr=0 need rows 0-2; row 3 holds the centers.
  LDROW(r0, 0)
  LDROW(r1, 1)
  LDROW(r2, 2)
  LDROW(r3, 3)
  float cen[4] = {r3[6], r3[7], r3[8], r3[9]};
  LDROW(r4, 4)  // prefetch for phase B
  DO_TAP9(0, r0, r1, r2, 0, yok0 && xokL[p], -2, -2)
  DO_TAPV(1, r0, r1, r2, yok0)
  DO_TAP9(2, r0, r1, r2, 8, yok0 && xokR[p], -2, -2)
  LDROW(r5, 5)  // prefetch for phase C
  LDROW(r6, 6)
  // Phase B: taps jr=1 need rows 2-4
  DO_TAPH(3, r3, 0, xokL[p])
  DO_TAP9(4, r2, r3, r4, 4, true, 0, 0)
  DO_TAPH(5, r3, 8, xokR[p])
  // Phase C: taps jr=2 need rows 4-6
  DO_TAP9(6, r4, r5, r6, 0, yok2 && xokL[p], -2, -2)
  DO_TAPV(7, r4, r5, r6, yok2)
  DO_TAP9(8, r4, r5, r6, 8, yok2 && xokR[p], -2, -2)
}

// ---------------- fallback (round-1 kernel) if ws too small ------------------
__global__ __launch_bounds__(256) void depth_offset_fallback(
    const float* __restrict__ d, int* __restrict__ out) {
  int idx = blockIdx.x * blockDim.x + threadIdx.x;
  if (idx >= BATCH * IH * IW) return;
  int ox = idx % IW;
  int t = idx / IW;
  int oy = t % IH;
  int b = t / IH;
  const float* db = d + (size_t)b * (IH * IW);
  float center = db[oy * IW + ox];
  float nb[7][7];
#pragma unroll
  for (int i = 0; i < 7; ++i) {
    int y = oy + 2 * i - 6;
    bool yok = ((unsigned)y < (unsigned)IH);
#pragma unroll
    for (int jj = 0; jj < 7; ++jj) {
      int x = ox + 2 * jj - 6;
      float v = 0.0f;
      if (yok && ((unsigned)x < (unsigned)IW)) v = db[y * IW + x];
      nb[i][jj] = v;
    }
  }
  const size_t plane = (size_t)IH * IW;
  int* outb = out + (size_t)b * 18 * plane;
  size_t pix = (size_t)oy * IW + ox;
#pragma unroll
  for (int j = 0; j < 9; ++j) {
    const int jr = j / 3, jc = j % 3;
    int Y = oy + 4 * (jr - 1);
    int X = ox + 4 * (jc - 1);
    bool jok = ((unsigned)Y < (unsigned)IH) && ((unsigned)X < (unsigned)IW);
    float best = __builtin_huge_valf();
    int bk = 0;
#pragma unroll
    for (int k = 0; k < 9; ++k) {
      const int kr = k / 3, kc = k % 3;
      bool allowed = true;
      if (j == 1 || j == 7) allowed = (kc == 1);
      if (j == 3 || j == 5) allowed = (kr == 1);
      if (!allowed) continue;
      float v = jok ? nb[2 * jr + kr][2 * jc + kc] : 0.0f;
      float diff = fabsf(v - center);
      if (diff < best) {
        best = diff;
        bk = k;
      }
    }
    outb[(size_t)j * plane + pix] = (bk / 3 - 1) * 2;
    outb[(size_t)(9 + j) * plane + pix] = (bk % 3 - 1) * 2;
  }
}

extern "C" void kernel_launch(void* const* d_in, const int* in_sizes, int n_in,
                              void* d_out, int out_size, void* d_ws, size_t ws_size,
                              hipStream_t stream) {
  const float* depth = (const float*)d_in[0];
  int* out = (int*)d_out;
  if (ws_size >= PADBYTES) {
    float* pd = (float*)d_ws;
    const int n4 = BATCH * PPH * (PPW / 4);
    pad_kernel<<<(n4 + 255) / 256, 256, 0, stream>>>(depth, pd);
    const int ngroups = BATCH * IH * (IW / 4);
    depth_offset_main<<<(ngroups + 255) / 256, 256, 0, stream>>>(pd, out);
  } else {
    const int total = BATCH * IH * IW;
    depth_offset_fallback<<<(total + 255) / 256, 256, 0, stream>>>(depth, out);
  }
}